// Round 3
// baseline (5781.107 us; speedup 1.0000x reference)
//
#include <hip/hip_runtime.h>

#define S_LEN 512
#define BATCH 64
#define EDIM  128
#define HDIM  256
#define GDIM  1024   // 4*H
#define TDIM  64
#define NROW  32768  // S*B

typedef __attribute__((ext_vector_type(8))) short short8;
typedef __attribute__((ext_vector_type(4))) short short4v;
typedef __attribute__((ext_vector_type(4))) unsigned short us4;
typedef __attribute__((ext_vector_type(4))) float f32x4;

__device__ __forceinline__ unsigned short f2bf(float f) {
  unsigned u = __float_as_uint(f);
  u += 0x7FFFu + ((u >> 16) & 1u);   // RNE
  return (unsigned short)(u >> 16);
}
__device__ __forceinline__ float bf2f(unsigned short h) {
  return __uint_as_float(((unsigned)h) << 16);
}
__device__ __forceinline__ float sigm(float x) {
  float e = __expf(-x);
  return __builtin_amdgcn_rcpf(1.f + e);
}
__device__ __forceinline__ float tanh_(float x) {
  float e = __expf(2.f * x);
  return 1.f - 2.f * __builtin_amdgcn_rcpf(e + 1.f);
}

// ---------------- Kernel 0: pack W_hh into MFMA-fragment order (bf16) ------
// frag id = (((dir*16 + w)*8 + kk)*4 + gt), lane l: 8 bf16 = W[gt*256+w*16+cl][kk*32+q*8 ..+7]
__global__ __launch_bounds__(256) void k_pack(
    const float* __restrict__ Whf, const float* __restrict__ Whb,
    unsigned short* __restrict__ wpk) {
  const int fid = blockIdx.x * 256 + threadIdx.x;   // 65536 lane-frags
  const int l = fid & 63;
  int rest = fid >> 6;
  const int gt = rest & 3;  rest >>= 2;
  const int kk = rest & 7;  rest >>= 3;
  const int w  = rest & 15;
  const int dir = rest >> 4;
  const int q = l >> 4, cl = l & 15;
  const float* Wh = dir ? Whb : Whf;
  const float* src = Wh + (size_t)(gt * 256 + w * 16 + cl) * HDIM + kk * 32 + q * 8;
  float4 v0 = *(const float4*)src;
  float4 v1 = *(const float4*)(src + 4);
  short8 t8;
  t8[0] = (short)f2bf(v0.x); t8[1] = (short)f2bf(v0.y);
  t8[2] = (short)f2bf(v0.z); t8[3] = (short)f2bf(v0.w);
  t8[4] = (short)f2bf(v1.x); t8[5] = (short)f2bf(v1.y);
  t8[6] = (short)f2bf(v1.z); t8[7] = (short)f2bf(v1.w);
  *(short8*)(wpk + (size_t)fid * 8) = t8;
}

// ---------------- Kernel 1: gather + input projection (both directions) ----
// xqT layout: [s][gatecol(1024)][batch(64)] bf16.
__global__ __launch_bounds__(512) void k_proj(
    const int* __restrict__ tok, const float* __restrict__ emb,
    const float* __restrict__ Wf, const float* __restrict__ bihf, const float* __restrict__ bhhf,
    const float* __restrict__ Wb, const float* __restrict__ bihb, const float* __restrict__ bhhb,
    unsigned short* __restrict__ xqf, unsigned short* __restrict__ xqb) {
  __shared__ short xt[256 * 136];
  const int tid = threadIdx.x;
  const int rowbase = blockIdx.x * 256;
  const int dir = blockIdx.y;
  const float* W  = dir ? Wb   : Wf;
  const float* bi = dir ? bihb : bihf;
  const float* bh = dir ? bhhb : bhhf;
  unsigned short* xq = dir ? xqb : xqf;

  for (int i = tid; i < 256 * 32; i += 512) {
    int row = i >> 5, c4 = (i & 31) << 2;
    int t = tok[rowbase + row];
    float4 v = *(const float4*)(emb + (size_t)t * EDIM + c4);
    short4v p;
    p.x = (short)f2bf(v.x); p.y = (short)f2bf(v.y);
    p.z = (short)f2bf(v.z); p.w = (short)f2bf(v.w);
    *(short4v*)&xt[row * 136 + c4] = p;
  }
  __syncthreads();

  const int w = tid >> 6, l = tid & 63, q = l >> 4, cl = l & 15;

  short8 a[2][4];
#pragma unroll
  for (int rt = 0; rt < 2; ++rt)
#pragma unroll
    for (int kk = 0; kk < 4; ++kk)
      a[rt][kk] = *(const short8*)&xt[((2 * w + rt) * 16 + cl) * 136 + kk * 32 + q * 8];

  for (int ct = 0; ct < 64; ++ct) {
    const int colg = ct * 16 + cl;
    short8 bw[4];
#pragma unroll
    for (int kk = 0; kk < 4; ++kk) {
      const float* wp = W + (size_t)colg * EDIM + kk * 32 + q * 8;
      float4 w0 = *(const float4*)wp;
      float4 w1 = *(const float4*)(wp + 4);
      short8 t8;
      t8[0] = (short)f2bf(w0.x); t8[1] = (short)f2bf(w0.y);
      t8[2] = (short)f2bf(w0.z); t8[3] = (short)f2bf(w0.w);
      t8[4] = (short)f2bf(w1.x); t8[5] = (short)f2bf(w1.y);
      t8[6] = (short)f2bf(w1.z); t8[7] = (short)f2bf(w1.w);
      bw[kk] = t8;
    }
    float bias = bi[colg] + bh[colg];
#pragma unroll
    for (int rt = 0; rt < 2; ++rt) {
      f32x4 acc = {bias, bias, bias, bias};
#pragma unroll
      for (int kk = 0; kk < 4; ++kk)
        acc = __builtin_amdgcn_mfma_f32_16x16x32_bf16(a[rt][kk], bw[kk], acc, 0, 0, 0);
      const int rowg = rowbase + (2 * w + rt) * 16 + q * 4;
      const int s = rowg >> 6, b0 = rowg & 63;
      us4 p;
      p[0] = f2bf(acc[0]); p[1] = f2bf(acc[1]);
      p[2] = f2bf(acc[2]); p[3] = f2bf(acc[3]);
      *(us4*)&xq[((size_t)s * GDIM + colg) * BATCH + b0] = p;
    }
  }
}

// ---------------- Kernel 2: LSTM scans (persistent, W streamed from L2) ----
// grid = 8: dir = bx&1, 16-row batch-group = bx>>1. 16 waves; wave owns 64 gate-cols.
// W: pre-packed bf16 frags, 3-slot rolling register pipeline, L2-resident.
__global__ __launch_bounds__(1024) void k_lstm(
    const unsigned short* __restrict__ wpk,
    const unsigned short* __restrict__ xqf, const unsigned short* __restrict__ xqb,
    unsigned short* __restrict__ hq) {
  __shared__ short hb0[16][264];
  __shared__ short hb1[16][264];
  const int tid = threadIdx.x;
  const int dir = blockIdx.x & 1, bg = blockIdx.x >> 1;
  const int w = tid >> 6, l = tid & 63, q = l >> 4, cl = l & 15;
  const int hidx = w * 16 + cl;
  const int brow = bg * 16 + q * 4;
  const char* xqB = (const char*)(dir ? xqb : xqf);
  // per-lane W stream base (frag (kk,gt) at +((kk*4+gt)*1024) bytes)
  const char* wlp = (const char*)wpk + (size_t)(dir * 16 + w) * 32768 + l * 16;

  for (int i = tid; i < 16 * 264; i += 1024) { ((short*)hb0)[i] = 0; ((short*)hb1)[i] = 0; }

  int xlane[4];
#pragma unroll
  for (int gt = 0; gt < 4; ++gt)
    xlane[gt] = ((gt * 256 + hidx) * BATCH + brow) * 2;
  const int hq_lbyte = (brow * 512 + dir * 256 + hidx) * 2;

  const int sd  = dir ? -(GDIM * BATCH * 2) : (GDIM * BATCH * 2);
  const int hsd = dir ? -(BATCH * 512 * 2)  : (BATCH * 512 * 2);
  const int s0 = dir ? (S_LEN - 1) : 0;
  int xoff   = s0 * (GDIM * BATCH * 2);   // offset of NEXT xp tile to load
  int hq_soff = s0 * (BATCH * 512 * 2);

  // W rolling slots (persist across steps) + xp single buffer
  short8 wbuf[3][4];
  us4 xp[4];

  // prologue: issue W groups kk=0,1 and step-0 xp
#pragma unroll
  for (int kk = 0; kk < 2; ++kk)
#pragma unroll
    for (int gt = 0; gt < 4; ++gt)
      wbuf[kk][gt] = *(const short8*)(wlp + (kk * 4 + gt) * 1024);
#pragma unroll
  for (int gt = 0; gt < 4; ++gt)
    xp[gt] = *(const us4*)(xqB + xoff + xlane[gt]);
  xoff += sd;

  float cst[4] = {0.f, 0.f, 0.f, 0.f};
  __syncthreads();

#define STEP_BODY(RB, WB, T) {                                               \
    f32x4 acc[4];                                                            \
    const f32x4 zz = {0.f, 0.f, 0.f, 0.f};                                   \
    _Pragma("unroll") for (int gt = 0; gt < 4; ++gt) acc[gt] = zz;           \
    short8 a0[4];                                                            \
    _Pragma("unroll") for (int kk = 0; kk < 4; ++kk)                         \
      a0[kk] = *(const short8*)&RB[cl][kk * 32 + q * 8];                     \
    _Pragma("unroll") for (int kk = 0; kk < 4; ++kk) {                       \
      _Pragma("unroll") for (int gt = 0; gt < 4; ++gt)                       \
        wbuf[(kk + 2) % 3][gt] = *(const short8*)(wlp + ((kk + 2) * 4 + gt) * 1024); \
      _Pragma("unroll") for (int gt = 0; gt < 4; ++gt)                       \
        acc[gt] = __builtin_amdgcn_mfma_f32_16x16x32_bf16(a0[kk], wbuf[kk % 3][gt], acc[gt], 0, 0, 0); \
    }                                                                        \
    short8 a1[4];                                                            \
    _Pragma("unroll") for (int kk = 0; kk < 4; ++kk)                         \
      a1[kk] = *(const short8*)&RB[cl][(kk + 4) * 32 + q * 8];               \
    _Pragma("unroll") for (int kk = 4; kk < 8; ++kk) {                       \
      if (kk < 6) {                                                          \
        _Pragma("unroll") for (int gt = 0; gt < 4; ++gt)                     \
          wbuf[(kk + 2) % 3][gt] = *(const short8*)(wlp + ((kk + 2) * 4 + gt) * 1024); \
      }                                                                      \
      _Pragma("unroll") for (int gt = 0; gt < 4; ++gt)                       \
        acc[gt] = __builtin_amdgcn_mfma_f32_16x16x32_bf16(a1[kk - 4], wbuf[kk % 3][gt], acc[gt], 0, 0, 0); \
    }                                                                        \
    /* prefetch next step's first two W groups (same addresses every step) */\
    _Pragma("unroll") for (int kk = 0; kk < 2; ++kk)                         \
      _Pragma("unroll") for (int gt = 0; gt < 4; ++gt)                       \
        wbuf[kk][gt] = *(const short8*)(wlp + (kk * 4 + gt) * 1024);         \
    _Pragma("unroll") for (int r = 0; r < 4; ++r) {                          \
      float gi = sigm(acc[0][r] + bf2f(xp[0][r]));                           \
      float gf = sigm(acc[1][r] + bf2f(xp[1][r]));                           \
      float gg = tanh_(acc[2][r] + bf2f(xp[2][r]));                          \
      float go = sigm(acc[3][r] + bf2f(xp[3][r]));                           \
      float cn = gf * cst[r] + gi * gg;                                      \
      cst[r] = cn;                                                           \
      unsigned short hbv = f2bf(go * tanh_(cn));                             \
      WB[q * 4 + r][hidx] = (short)hbv;                                      \
      *(unsigned short*)((char*)hq + hq_soff + hq_lbyte + r * 1024) = hbv;   \
    }                                                                        \
    hq_soff += hsd;                                                          \
    /* prefetch next step's xp */                                            \
    _Pragma("unroll") for (int gt = 0; gt < 4; ++gt)                         \
      xp[gt] = *(const us4*)(xqB + xoff + xlane[gt]);                        \
    if ((T) < S_LEN - 2) xoff += sd;                                         \
    asm volatile("s_waitcnt lgkmcnt(0)\n\ts_barrier" ::: "memory");          \
  }

  for (int it = 0; it < S_LEN / 2; ++it) {
    const int t = 2 * it;
    STEP_BODY(hb0, hb1, t);
    STEP_BODY(hb1, hb0, t + 1);
  }
#undef STEP_BODY
}

// ---------------- Kernel 3: output projection ------------------------------
__global__ __launch_bounds__(256) void k_out(
    const unsigned short* __restrict__ hq, const float* __restrict__ Wo,
    const float* __restrict__ bo, float* __restrict__ out) {
  __shared__ short wlds[64 * 520];
  const int tid = threadIdx.x;
  for (int i = tid; i < 64 * 128; i += 256) {
    int row = i >> 7, c4 = (i & 127) << 2;
    float4 v = *(const float4*)(Wo + (size_t)row * 512 + c4);
    short4v p;
    p.x = (short)f2bf(v.x); p.y = (short)f2bf(v.y);
    p.z = (short)f2bf(v.z); p.w = (short)f2bf(v.w);
    *(short4v*)&wlds[row * 520 + c4] = p;
  }
  __syncthreads();

  const int w = tid >> 6, l = tid & 63, q = l >> 4, cl = l & 15;
  const int rtb = blockIdx.x * 64 + w * 16;

  short8 a[16];
#pragma unroll
  for (int kk = 0; kk < 16; ++kk)
    a[kk] = *(const short8*)&hq[(size_t)(rtb + cl) * 512 + kk * 32 + q * 8];

#pragma unroll
  for (int ct = 0; ct < 4; ++ct) {
    float bias = bo[ct * 16 + cl];
    f32x4 acc = {bias, bias, bias, bias};
#pragma unroll
    for (int kk = 0; kk < 16; ++kk) {
      short8 b = *(const short8*)&wlds[(ct * 16 + cl) * 520 + kk * 32 + q * 8];
      acc = __builtin_amdgcn_mfma_f32_16x16x32_bf16(a[kk], b, acc, 0, 0, 0);
    }
#pragma unroll
    for (int r = 0; r < 4; ++r)
      out[(size_t)(rtb + q * 4 + r) * TDIM + ct * 16 + cl] = acc[r];
  }
}

extern "C" void kernel_launch(void* const* d_in, const int* in_sizes, int n_in,
                              void* d_out, int out_size, void* d_ws, size_t ws_size,
                              hipStream_t stream) {
  const int*   tok  = (const int*)d_in[0];
  const float* emb  = (const float*)d_in[1];
  const float* Wihf = (const float*)d_in[2];
  const float* Whhf = (const float*)d_in[3];
  const float* bihf = (const float*)d_in[4];
  const float* bhhf = (const float*)d_in[5];
  const float* Wihb = (const float*)d_in[6];
  const float* Whhb = (const float*)d_in[7];
  const float* bihb = (const float*)d_in[8];
  const float* bhhb = (const float*)d_in[9];
  const float* Wo   = (const float*)d_in[10];
  const float* bo   = (const float*)d_in[11];
  float* out = (float*)d_out;

  char* ws = (char*)d_ws;
  unsigned short* xqf = (unsigned short*)ws;                                  // 64 MiB
  unsigned short* xqb = (unsigned short*)(ws + (size_t)NROW * GDIM * 2);      // 64 MiB
  unsigned short* hq  = (unsigned short*)(ws + (size_t)NROW * GDIM * 4);      // 32 MiB
  // packed W parked in d_out (1 MiB of 8 MiB); k_out fully overwrites d_out later
  unsigned short* wpk = (unsigned short*)d_out;

  k_pack<<<256, 256, 0, stream>>>(Whhf, Whhb, wpk);
  k_proj<<<dim3(128, 2), 512, 0, stream>>>(tok, emb, Wihf, bihf, bhhf,
                                           Wihb, bihb, bhhb, xqf, xqb);
  k_lstm<<<8, 1024, 0, stream>>>(wpk, xqf, xqb, hq);
  k_out<<<512, 256, 0, stream>>>(hq, Wo, bo, out);
}

// Round 4
// 5730.254 us; speedup vs baseline: 1.0089x; 1.0089x over previous
//
#include <hip/hip_runtime.h>

#define S_LEN 512
#define BATCH 64
#define EDIM  128
#define HDIM  256
#define GDIM  1024   // 4*H
#define TDIM  64
#define NROW  32768  // S*B

typedef __attribute__((ext_vector_type(8))) short short8;
typedef __attribute__((ext_vector_type(4))) short short4v;
typedef __attribute__((ext_vector_type(4))) unsigned short us4;
typedef __attribute__((ext_vector_type(4))) float f32x4;

__device__ __forceinline__ unsigned short f2bf(float f) {
  unsigned u = __float_as_uint(f);
  u += 0x7FFFu + ((u >> 16) & 1u);   // RNE
  return (unsigned short)(u >> 16);
}
__device__ __forceinline__ float bf2f(unsigned short h) {
  return __uint_as_float(((unsigned)h) << 16);
}
__device__ __forceinline__ float sigm(float x) {
  float e = __expf(-x);
  return __builtin_amdgcn_rcpf(1.f + e);
}
__device__ __forceinline__ float tanh_(float x) {
  float e = __expf(2.f * x);
  return 1.f - 2.f * __builtin_amdgcn_rcpf(e + 1.f);
}

// ---------------- Kernel 0: pack W_hh into MFMA-fragment order (bf16) ------
// frag id = (((dir*16 + w)*8 + kk)*4 + gt), lane l: 8 bf16 = W[gt*256+w*16+cl][kk*32+q*8 ..+7]
__global__ __launch_bounds__(256) void k_pack(
    const float* __restrict__ Whf, const float* __restrict__ Whb,
    unsigned short* __restrict__ wpk) {
  const int fid = blockIdx.x * 256 + threadIdx.x;   // 65536 lane-frags
  const int l = fid & 63;
  int rest = fid >> 6;
  const int gt = rest & 3;  rest >>= 2;
  const int kk = rest & 7;  rest >>= 3;
  const int w  = rest & 15;
  const int dir = rest >> 4;
  const int q = l >> 4, cl = l & 15;
  const float* Wh = dir ? Whb : Whf;
  const float* src = Wh + (size_t)(gt * 256 + w * 16 + cl) * HDIM + kk * 32 + q * 8;
  float4 v0 = *(const float4*)src;
  float4 v1 = *(const float4*)(src + 4);
  short8 t8;
  t8[0] = (short)f2bf(v0.x); t8[1] = (short)f2bf(v0.y);
  t8[2] = (short)f2bf(v0.z); t8[3] = (short)f2bf(v0.w);
  t8[4] = (short)f2bf(v1.x); t8[5] = (short)f2bf(v1.y);
  t8[6] = (short)f2bf(v1.z); t8[7] = (short)f2bf(v1.w);
  *(short8*)(wpk + (size_t)fid * 8) = t8;
}

// ---------------- Kernel 1: gather + input projection (both directions) ----
// xqT layout: [s][gatecol(1024)][batch(64)] bf16.
__global__ __launch_bounds__(512) void k_proj(
    const int* __restrict__ tok, const float* __restrict__ emb,
    const float* __restrict__ Wf, const float* __restrict__ bihf, const float* __restrict__ bhhf,
    const float* __restrict__ Wb, const float* __restrict__ bihb, const float* __restrict__ bhhb,
    unsigned short* __restrict__ xqf, unsigned short* __restrict__ xqb) {
  __shared__ short xt[256 * 136];
  const int tid = threadIdx.x;
  const int rowbase = blockIdx.x * 256;
  const int dir = blockIdx.y;
  const float* W  = dir ? Wb   : Wf;
  const float* bi = dir ? bihb : bihf;
  const float* bh = dir ? bhhb : bhhf;
  unsigned short* xq = dir ? xqb : xqf;

  for (int i = tid; i < 256 * 32; i += 512) {
    int row = i >> 5, c4 = (i & 31) << 2;
    int t = tok[rowbase + row];
    float4 v = *(const float4*)(emb + (size_t)t * EDIM + c4);
    short4v p;
    p.x = (short)f2bf(v.x); p.y = (short)f2bf(v.y);
    p.z = (short)f2bf(v.z); p.w = (short)f2bf(v.w);
    *(short4v*)&xt[row * 136 + c4] = p;
  }
  __syncthreads();

  const int w = tid >> 6, l = tid & 63, q = l >> 4, cl = l & 15;

  short8 a[2][4];
#pragma unroll
  for (int rt = 0; rt < 2; ++rt)
#pragma unroll
    for (int kk = 0; kk < 4; ++kk)
      a[rt][kk] = *(const short8*)&xt[((2 * w + rt) * 16 + cl) * 136 + kk * 32 + q * 8];

  for (int ct = 0; ct < 64; ++ct) {
    const int colg = ct * 16 + cl;
    short8 bw[4];
#pragma unroll
    for (int kk = 0; kk < 4; ++kk) {
      const float* wp = W + (size_t)colg * EDIM + kk * 32 + q * 8;
      float4 w0 = *(const float4*)wp;
      float4 w1 = *(const float4*)(wp + 4);
      short8 t8;
      t8[0] = (short)f2bf(w0.x); t8[1] = (short)f2bf(w0.y);
      t8[2] = (short)f2bf(w0.z); t8[3] = (short)f2bf(w0.w);
      t8[4] = (short)f2bf(w1.x); t8[5] = (short)f2bf(w1.y);
      t8[6] = (short)f2bf(w1.z); t8[7] = (short)f2bf(w1.w);
      bw[kk] = t8;
    }
    float bias = bi[colg] + bh[colg];
#pragma unroll
    for (int rt = 0; rt < 2; ++rt) {
      f32x4 acc = {bias, bias, bias, bias};
#pragma unroll
      for (int kk = 0; kk < 4; ++kk)
        acc = __builtin_amdgcn_mfma_f32_16x16x32_bf16(a[rt][kk], bw[kk], acc, 0, 0, 0);
      const int rowg = rowbase + (2 * w + rt) * 16 + q * 4;
      const int s = rowg >> 6, b0 = rowg & 63;
      us4 p;
      p[0] = f2bf(acc[0]); p[1] = f2bf(acc[1]);
      p[2] = f2bf(acc[2]); p[3] = f2bf(acc[3]);
      *(us4*)&xq[((size_t)s * GDIM + colg) * BATCH + b0] = p;
    }
  }
}

// ---------------- Kernel 2: LSTM scans (persistent, W streamed from L2) ----
// grid = 8: dir = bx&1, 16-row batch-group = bx>>1. 16 waves; wave owns 64 gate-cols.
// 128-VGPR budget (4 waves/SIMD): stationary kk0 + 2-deep rolling stream kk1..7.
__global__ __launch_bounds__(1024, 4) __attribute__((amdgpu_waves_per_eu(4, 4)))
void k_lstm(
    const unsigned short* __restrict__ wpk,
    const unsigned short* __restrict__ xqf, const unsigned short* __restrict__ xqb,
    unsigned short* __restrict__ hq) {
  __shared__ short hb0[16][264];
  __shared__ short hb1[16][264];
  const int tid = threadIdx.x;
  const int dir = blockIdx.x & 1, bg = blockIdx.x >> 1;
  const int w = tid >> 6, l = tid & 63, q = l >> 4, cl = l & 15;
  const int hidx = w * 16 + cl;
  const int brow = bg * 16 + q * 4;
  const char* xqB = (const char*)(dir ? xqb : xqf);
  // per-lane W stream base (frag (kk,gt) at +((kk*4+gt)*1024) bytes)
  const char* wlp = (const char*)wpk + (size_t)(dir * 16 + w) * 32768 + l * 16;

  for (int i = tid; i < 16 * 264; i += 1024) { ((short*)hb0)[i] = 0; ((short*)hb1)[i] = 0; }

  int xlane[4];
#pragma unroll
  for (int gt = 0; gt < 4; ++gt)
    xlane[gt] = ((gt * 256 + hidx) * BATCH + brow) * 2;
  const int hq_lbyte = (brow * 512 + dir * 256 + hidx) * 2;

  const int sd  = dir ? -(GDIM * BATCH * 2) : (GDIM * BATCH * 2);
  const int hsd = dir ? -(BATCH * 512 * 2)  : (BATCH * 512 * 2);
  const int s0 = dir ? (S_LEN - 1) : 0;
  int xoff    = s0 * (GDIM * BATCH * 2);
  int hq_soff = s0 * (BATCH * 512 * 2);

#define LOADW(DST, KK)                                                        \
    _Pragma("unroll") for (int gt = 0; gt < 4; ++gt)                          \
      DST[gt] = *(const short8*)(wlp + ((KK) * 4 + gt) * 1024);
#define MF(AV, WV)                                                            \
    _Pragma("unroll") for (int gt = 0; gt < 4; ++gt)                          \
      acc[gt] = __builtin_amdgcn_mfma_f32_16x16x32_bf16(AV, WV[gt], acc[gt], 0, 0, 0);

  // stationary W (kk=0) + rolling slots
  short8 wst[4];
  short8 wrlA[4], wrlB[4];
  us4 xp[4];

  LOADW(wst, 0)
  LOADW(wrlB, 1)
  LOADW(wrlA, 2)
#pragma unroll
  for (int gt = 0; gt < 4; ++gt)
    xp[gt] = *(const us4*)(xqB + xoff + xlane[gt]);
  xoff += sd;

  float cst[4] = {0.f, 0.f, 0.f, 0.f};
  __syncthreads();

#define STEP_BODY(RB, WB, T) {                                               \
    f32x4 acc[4];                                                            \
    const f32x4 zz = {0.f, 0.f, 0.f, 0.f};                                   \
    _Pragma("unroll") for (int gt = 0; gt < 4; ++gt) acc[gt] = zz;           \
    short8 a0[4];                                                            \
    _Pragma("unroll") for (int kk = 0; kk < 4; ++kk)                         \
      a0[kk] = *(const short8*)&RB[cl][kk * 32 + q * 8];                     \
    MF(a0[0], wst)                      /* kk0 (stationary) */               \
    MF(a0[1], wrlB)  LOADW(wrlB, 3)     /* kk1, refill slotB<-kk3 */         \
    MF(a0[2], wrlA)  LOADW(wrlA, 4)     /* kk2, refill slotA<-kk4 */         \
    short8 a1[4];                                                            \
    _Pragma("unroll") for (int kk = 0; kk < 4; ++kk)                         \
      a1[kk] = *(const short8*)&RB[cl][(kk + 4) * 32 + q * 8];               \
    MF(a0[3], wrlB)  LOADW(wrlB, 5)     /* kk3 */                            \
    MF(a1[0], wrlA)  LOADW(wrlA, 6)     /* kk4 */                            \
    MF(a1[1], wrlB)  LOADW(wrlB, 7)     /* kk5 */                            \
    MF(a1[2], wrlA)  LOADW(wrlA, 2)     /* kk6, prefetch NEXT step kk2 */    \
    MF(a1[3], wrlB)  LOADW(wrlB, 1)     /* kk7, prefetch NEXT step kk1 */    \
    _Pragma("unroll") for (int r = 0; r < 4; ++r) {                          \
      float gi = sigm(acc[0][r] + bf2f(xp[0][r]));                           \
      float gf = sigm(acc[1][r] + bf2f(xp[1][r]));                           \
      float gg = tanh_(acc[2][r] + bf2f(xp[2][r]));                          \
      float go = sigm(acc[3][r] + bf2f(xp[3][r]));                           \
      float cn = gf * cst[r] + gi * gg;                                      \
      cst[r] = cn;                                                           \
      unsigned short hbv = f2bf(go * tanh_(cn));                             \
      WB[q * 4 + r][hidx] = (short)hbv;                                      \
      *(unsigned short*)((char*)hq + hq_soff + hq_lbyte + r * 1024) = hbv;   \
    }                                                                        \
    hq_soff += hsd;                                                          \
    _Pragma("unroll") for (int gt = 0; gt < 4; ++gt)                         \
      xp[gt] = *(const us4*)(xqB + xoff + xlane[gt]);                        \
    if ((T) < S_LEN - 2) xoff += sd;                                         \
    asm volatile("s_waitcnt lgkmcnt(0)\n\ts_barrier" ::: "memory");          \
  }

  for (int it = 0; it < S_LEN / 2; ++it) {
    const int t = 2 * it;
    STEP_BODY(hb0, hb1, t);
    STEP_BODY(hb1, hb0, t + 1);
  }
#undef STEP_BODY
#undef LOADW
#undef MF
}

// ---------------- Kernel 3: output projection ------------------------------
__global__ __launch_bounds__(256) void k_out(
    const unsigned short* __restrict__ hq, const float* __restrict__ Wo,
    const float* __restrict__ bo, float* __restrict__ out) {
  __shared__ short wlds[64 * 520];
  const int tid = threadIdx.x;
  for (int i = tid; i < 64 * 128; i += 256) {
    int row = i >> 7, c4 = (i & 127) << 2;
    float4 v = *(const float4*)(Wo + (size_t)row * 512 + c4);
    short4v p;
    p.x = (short)f2bf(v.x); p.y = (short)f2bf(v.y);
    p.z = (short)f2bf(v.z); p.w = (short)f2bf(v.w);
    *(short4v*)&wlds[row * 520 + c4] = p;
  }
  __syncthreads();

  const int w = tid >> 6, l = tid & 63, q = l >> 4, cl = l & 15;
  const int rtb = blockIdx.x * 64 + w * 16;

  short8 a[16];
#pragma unroll
  for (int kk = 0; kk < 16; ++kk)
    a[kk] = *(const short8*)&hq[(size_t)(rtb + cl) * 512 + kk * 32 + q * 8];

#pragma unroll
  for (int ct = 0; ct < 4; ++ct) {
    float bias = bo[ct * 16 + cl];
    f32x4 acc = {bias, bias, bias, bias};
#pragma unroll
    for (int kk = 0; kk < 16; ++kk) {
      short8 b = *(const short8*)&wlds[(ct * 16 + cl) * 520 + kk * 32 + q * 8];
      acc = __builtin_amdgcn_mfma_f32_16x16x32_bf16(a[kk], b, acc, 0, 0, 0);
    }
#pragma unroll
    for (int r = 0; r < 4; ++r)
      out[(size_t)(rtb + q * 4 + r) * TDIM + ct * 16 + cl] = acc[r];
  }
}

extern "C" void kernel_launch(void* const* d_in, const int* in_sizes, int n_in,
                              void* d_out, int out_size, void* d_ws, size_t ws_size,
                              hipStream_t stream) {
  const int*   tok  = (const int*)d_in[0];
  const float* emb  = (const float*)d_in[1];
  const float* Wihf = (const float*)d_in[2];
  const float* Whhf = (const float*)d_in[3];
  const float* bihf = (const float*)d_in[4];
  const float* bhhf = (const float*)d_in[5];
  const float* Wihb = (const float*)d_in[6];
  const float* Whhb = (const float*)d_in[7];
  const float* bihb = (const float*)d_in[8];
  const float* bhhb = (const float*)d_in[9];
  const float* Wo   = (const float*)d_in[10];
  const float* bo   = (const float*)d_in[11];
  float* out = (float*)d_out;

  char* ws = (char*)d_ws;
  unsigned short* xqf = (unsigned short*)ws;                                  // 64 MiB
  unsigned short* xqb = (unsigned short*)(ws + (size_t)NROW * GDIM * 2);      // 64 MiB
  unsigned short* hq  = (unsigned short*)(ws + (size_t)NROW * GDIM * 4);      // 32 MiB
  // packed W parked in d_out (1 MiB of 8 MiB); k_out fully overwrites d_out later
  unsigned short* wpk = (unsigned short*)d_out;

  k_pack<<<256, 256, 0, stream>>>(Whhf, Whhb, wpk);
  k_proj<<<dim3(128, 2), 512, 0, stream>>>(tok, emb, Wihf, bihf, bhhf,
                                           Wihb, bihb, bhhb, xqf, xqb);
  k_lstm<<<8, 1024, 0, stream>>>(wpk, xqf, xqb, hq);
  k_out<<<512, 256, 0, stream>>>(hq, Wo, bo, out);
}

// Round 5
// 3436.530 us; speedup vs baseline: 1.6823x; 1.6675x over previous
//
#include <hip/hip_runtime.h>

#define S_LEN 512
#define BATCH 64
#define EDIM  128
#define HDIM  256
#define GDIM  1024   // 4*H
#define TDIM  64
#define NROW  32768  // S*B

typedef __attribute__((ext_vector_type(8))) short short8;
typedef __attribute__((ext_vector_type(4))) short short4v;
typedef __attribute__((ext_vector_type(4))) unsigned short us4;
typedef __attribute__((ext_vector_type(4))) float f32x4;

__device__ __forceinline__ unsigned short f2bf(float f) {
  unsigned u = __float_as_uint(f);
  u += 0x7FFFu + ((u >> 16) & 1u);   // RNE
  return (unsigned short)(u >> 16);
}
__device__ __forceinline__ float bf2f(unsigned short h) {
  return __uint_as_float(((unsigned)h) << 16);
}
__device__ __forceinline__ float sigm(float x) {
  float e = __expf(-x);
  return __builtin_amdgcn_rcpf(1.f + e);
}
__device__ __forceinline__ float tanh_(float x) {
  float e = __expf(2.f * x);
  return 1.f - 2.f * __builtin_amdgcn_rcpf(e + 1.f);
}

// ---------------- Kernel 0: pack W_hh into MFMA-fragment order (bf16) ------
// frag id = (((dir*16 + w)*8 + kk)*4 + gt), lane l: 8 bf16 = W[gt*256+w*16+cl][kk*32+q*8 ..+7]
__global__ __launch_bounds__(256) void k_pack(
    const float* __restrict__ Whf, const float* __restrict__ Whb,
    unsigned short* __restrict__ wpk) {
  const int fid = blockIdx.x * 256 + threadIdx.x;   // 65536 lane-frags
  const int l = fid & 63;
  int rest = fid >> 6;
  const int gt = rest & 3;  rest >>= 2;
  const int kk = rest & 7;  rest >>= 3;
  const int w  = rest & 15;
  const int dir = rest >> 4;
  const int q = l >> 4, cl = l & 15;
  const float* Wh = dir ? Whb : Whf;
  const float* src = Wh + (size_t)(gt * 256 + w * 16 + cl) * HDIM + kk * 32 + q * 8;
  float4 v0 = *(const float4*)src;
  float4 v1 = *(const float4*)(src + 4);
  short8 t8;
  t8[0] = (short)f2bf(v0.x); t8[1] = (short)f2bf(v0.y);
  t8[2] = (short)f2bf(v0.z); t8[3] = (short)f2bf(v0.w);
  t8[4] = (short)f2bf(v1.x); t8[5] = (short)f2bf(v1.y);
  t8[6] = (short)f2bf(v1.z); t8[7] = (short)f2bf(v1.w);
  *(short8*)(wpk + (size_t)fid * 8) = t8;
}

// ---------------- Kernel 1: gather + input projection (both directions) ----
// xqT layout: [s][gatecol(1024)][batch(64)] bf16.
__global__ __launch_bounds__(512) void k_proj(
    const int* __restrict__ tok, const float* __restrict__ emb,
    const float* __restrict__ Wf, const float* __restrict__ bihf, const float* __restrict__ bhhf,
    const float* __restrict__ Wb, const float* __restrict__ bihb, const float* __restrict__ bhhb,
    unsigned short* __restrict__ xqf, unsigned short* __restrict__ xqb) {
  __shared__ short xt[256 * 136];
  const int tid = threadIdx.x;
  const int rowbase = blockIdx.x * 256;
  const int dir = blockIdx.y;
  const float* W  = dir ? Wb   : Wf;
  const float* bi = dir ? bihb : bihf;
  const float* bh = dir ? bhhb : bhhf;
  unsigned short* xq = dir ? xqb : xqf;

  for (int i = tid; i < 256 * 32; i += 512) {
    int row = i >> 5, c4 = (i & 31) << 2;
    int t = tok[rowbase + row];
    float4 v = *(const float4*)(emb + (size_t)t * EDIM + c4);
    short4v p;
    p.x = (short)f2bf(v.x); p.y = (short)f2bf(v.y);
    p.z = (short)f2bf(v.z); p.w = (short)f2bf(v.w);
    *(short4v*)&xt[row * 136 + c4] = p;
  }
  __syncthreads();

  const int w = tid >> 6, l = tid & 63, q = l >> 4, cl = l & 15;

  short8 a[2][4];
#pragma unroll
  for (int rt = 0; rt < 2; ++rt)
#pragma unroll
    for (int kk = 0; kk < 4; ++kk)
      a[rt][kk] = *(const short8*)&xt[((2 * w + rt) * 16 + cl) * 136 + kk * 32 + q * 8];

  for (int ct = 0; ct < 64; ++ct) {
    const int colg = ct * 16 + cl;
    short8 bw[4];
#pragma unroll
    for (int kk = 0; kk < 4; ++kk) {
      const float* wp = W + (size_t)colg * EDIM + kk * 32 + q * 8;
      float4 w0 = *(const float4*)wp;
      float4 w1 = *(const float4*)(wp + 4);
      short8 t8;
      t8[0] = (short)f2bf(w0.x); t8[1] = (short)f2bf(w0.y);
      t8[2] = (short)f2bf(w0.z); t8[3] = (short)f2bf(w0.w);
      t8[4] = (short)f2bf(w1.x); t8[5] = (short)f2bf(w1.y);
      t8[6] = (short)f2bf(w1.z); t8[7] = (short)f2bf(w1.w);
      bw[kk] = t8;
    }
    float bias = bi[colg] + bh[colg];
#pragma unroll
    for (int rt = 0; rt < 2; ++rt) {
      f32x4 acc = {bias, bias, bias, bias};
#pragma unroll
      for (int kk = 0; kk < 4; ++kk)
        acc = __builtin_amdgcn_mfma_f32_16x16x32_bf16(a[rt][kk], bw[kk], acc, 0, 0, 0);
      const int rowg = rowbase + (2 * w + rt) * 16 + q * 4;
      const int s = rowg >> 6, b0 = rowg & 63;
      us4 p;
      p[0] = f2bf(acc[0]); p[1] = f2bf(acc[1]);
      p[2] = f2bf(acc[2]); p[3] = f2bf(acc[3]);
      *(us4*)&xq[((size_t)s * GDIM + colg) * BATCH + b0] = p;
    }
  }
}

// ---------------- Kernel 2: LSTM scans -------------------------------------
// grid = 8: dir = bx&1, 16-row batch-group = bx>>1. 16 waves; wave owns 64 gate-cols.
// W placement per wave (8 kk-groups of 4 frags):
//   kk0,kk1 -> registers (loaded once), kk2,kk3 -> LDS (staged once via global_load_lds),
//   kk4..7  -> streamed from L2 each step, issued early, consumed last.
__global__ __launch_bounds__(1024, 4) __attribute__((amdgpu_waves_per_eu(4, 4)))
void k_lstm(
    const unsigned short* __restrict__ wpk,
    const unsigned short* __restrict__ xqf, const unsigned short* __restrict__ xqb,
    unsigned short* __restrict__ hq) {
  __shared__ char wsl[131072];              // 16 waves x 2 groups x 4 frags x 1KB
  __shared__ short hb0[16][264];
  __shared__ short hb1[16][264];
  const int tid = threadIdx.x;
  const int dir = blockIdx.x & 1, bg = blockIdx.x >> 1;
  const int w = tid >> 6, l = tid & 63, q = l >> 4, cl = l & 15;
  const int hidx = w * 16 + cl;
  const int brow = bg * 16 + q * 4;
  const char* xqB = (const char*)(dir ? xqb : xqf);
  const char* wlp = (const char*)wpk + (size_t)(dir * 16 + w) * 32768 + l * 16;
  char* wslw = wsl + w * 8192;              // this wave's LDS W slab

  for (int i = tid; i < 16 * 264; i += 1024) { ((short*)hb0)[i] = 0; ((short*)hb1)[i] = 0; }

  // stage kk2,kk3 into LDS (async DMA; lane's 16B lands at slab + frag*1024 + l*16)
#pragma unroll
  for (int kr = 0; kr < 2; ++kr)
#pragma unroll
    for (int gt = 0; gt < 4; ++gt)
      __builtin_amdgcn_global_load_lds(
          (const unsigned int*)(wlp + ((2 + kr) * 4 + gt) * 1024),
          (unsigned int*)(wslw + (kr * 4 + gt) * 1024), 16, 0, 0);

#define LOADG(DST, KK)                                                        \
    _Pragma("unroll") for (int gt = 0; gt < 4; ++gt)                          \
      DST[gt] = *(const short8*)(wlp + ((KK) * 4 + gt) * 1024);
#define LOADL(DST, KR)                                                        \
    _Pragma("unroll") for (int gt = 0; gt < 4; ++gt)                          \
      DST[gt] = *(const short8*)(wslw + ((KR) * 4 + gt) * 1024 + l * 16);
#define MF(AV, WV)                                                            \
    _Pragma("unroll") for (int gt = 0; gt < 4; ++gt)                          \
      acc[gt] = __builtin_amdgcn_mfma_f32_16x16x32_bf16(AV, WV[gt], acc[gt], 0, 0, 0);

  // register-stationary kk0,kk1
  short8 wst0[4], wst1[4];
  LOADG(wst0, 0)
  LOADG(wst1, 1)

  int xlane[4];
#pragma unroll
  for (int gt = 0; gt < 4; ++gt)
    xlane[gt] = ((gt * 256 + hidx) * BATCH + brow) * 2;
  const int hq_lbyte = (brow * 512 + dir * 256 + hidx) * 2;

  const int sd  = dir ? -(GDIM * BATCH * 2) : (GDIM * BATCH * 2);
  const int hsd = dir ? -(BATCH * 512 * 2)  : (BATCH * 512 * 2);
  const int s0 = dir ? (S_LEN - 1) : 0;
  int xoff    = s0 * (GDIM * BATCH * 2);
  int hq_soff = s0 * (BATCH * 512 * 2);

  us4 xp[4];
#pragma unroll
  for (int gt = 0; gt < 4; ++gt)
    xp[gt] = *(const us4*)(xqB + xoff + xlane[gt]);
  xoff += sd;

  float cst[4] = {0.f, 0.f, 0.f, 0.f};
  __syncthreads();   // drains prologue DMAs + hbuf zeroing

#define STEP_BODY(RB, WB, T) {                                               \
    short8 sA[4], sB[4];                                                     \
    LOADG(sA, 4)  LOADG(sB, 5)          /* streamed, ~500cy flight */        \
    short8 a[8];                                                             \
    _Pragma("unroll") for (int kk = 0; kk < 4; ++kk)                         \
      a[kk] = *(const short8*)&RB[cl][kk * 32 + q * 8];                      \
    f32x4 acc[4];                                                            \
    const f32x4 zz = {0.f, 0.f, 0.f, 0.f};                                   \
    _Pragma("unroll") for (int gt = 0; gt < 4; ++gt) acc[gt] = zz;           \
    short8 wl[4];                                                            \
    LOADL(wl, 0)   MF(a[2], wl)         /* kk2 from LDS */                   \
    LOADL(wl, 1)   MF(a[3], wl)         /* kk3 from LDS */                   \
    MF(a[0], wst0)                      /* kk0 reg-stationary */             \
    MF(a[1], wst1)                      /* kk1 reg-stationary */             \
    _Pragma("unroll") for (int kk = 4; kk < 8; ++kk)                         \
      a[kk] = *(const short8*)&RB[cl][kk * 32 + q * 8];                      \
    MF(a[4], sA)   LOADG(sA, 6)         /* consume s, roll slot */           \
    MF(a[5], sB)   LOADG(sB, 7)                                              \
    MF(a[6], sA)                                                             \
    MF(a[7], sB)                                                             \
    _Pragma("unroll") for (int r = 0; r < 4; ++r) {                          \
      float gi = sigm(acc[0][r] + bf2f(xp[0][r]));                           \
      float gf = sigm(acc[1][r] + bf2f(xp[1][r]));                           \
      float gg = tanh_(acc[2][r] + bf2f(xp[2][r]));                          \
      float go = sigm(acc[3][r] + bf2f(xp[3][r]));                           \
      float cn = gf * cst[r] + gi * gg;                                      \
      cst[r] = cn;                                                           \
      unsigned short hbv = f2bf(go * tanh_(cn));                             \
      WB[q * 4 + r][hidx] = (short)hbv;                                      \
      *(unsigned short*)((char*)hq + hq_soff + hq_lbyte + r * 1024) = hbv;   \
    }                                                                        \
    hq_soff += hsd;                                                          \
    _Pragma("unroll") for (int gt = 0; gt < 4; ++gt)                         \
      xp[gt] = *(const us4*)(xqB + xoff + xlane[gt]);                        \
    if ((T) < S_LEN - 2) xoff += sd;                                         \
    asm volatile("s_waitcnt lgkmcnt(0)\n\ts_barrier" ::: "memory");          \
  }

  for (int it = 0; it < S_LEN / 2; ++it) {
    const int t = 2 * it;
    STEP_BODY(hb0, hb1, t);
    STEP_BODY(hb1, hb0, t + 1);
  }
#undef STEP_BODY
#undef LOADG
#undef LOADL
#undef MF
}

// ---------------- Kernel 3: output projection ------------------------------
__global__ __launch_bounds__(256) void k_out(
    const unsigned short* __restrict__ hq, const float* __restrict__ Wo,
    const float* __restrict__ bo, float* __restrict__ out) {
  __shared__ short wlds[64 * 520];
  const int tid = threadIdx.x;
  for (int i = tid; i < 64 * 128; i += 256) {
    int row = i >> 7, c4 = (i & 127) << 2;
    float4 v = *(const float4*)(Wo + (size_t)row * 512 + c4);
    short4v p;
    p.x = (short)f2bf(v.x); p.y = (short)f2bf(v.y);
    p.z = (short)f2bf(v.z); p.w = (short)f2bf(v.w);
    *(short4v*)&wlds[row * 520 + c4] = p;
  }
  __syncthreads();

  const int w = tid >> 6, l = tid & 63, q = l >> 4, cl = l & 15;
  const int rtb = blockIdx.x * 64 + w * 16;

  short8 a[16];
#pragma unroll
  for (int kk = 0; kk < 16; ++kk)
    a[kk] = *(const short8*)&hq[(size_t)(rtb + cl) * 512 + kk * 32 + q * 8];

#pragma unroll
  for (int ct = 0; ct < 4; ++ct) {
    float bias = bo[ct * 16 + cl];
    f32x4 acc = {bias, bias, bias, bias};
#pragma unroll
    for (int kk = 0; kk < 16; ++kk) {
      short8 b = *(const short8*)&wlds[(ct * 16 + cl) * 520 + kk * 32 + q * 8];
      acc = __builtin_amdgcn_mfma_f32_16x16x32_bf16(a[kk], b, acc, 0, 0, 0);
    }
#pragma unroll
    for (int r = 0; r < 4; ++r)
      out[(size_t)(rtb + q * 4 + r) * TDIM + ct * 16 + cl] = acc[r];
  }
}

extern "C" void kernel_launch(void* const* d_in, const int* in_sizes, int n_in,
                              void* d_out, int out_size, void* d_ws, size_t ws_size,
                              hipStream_t stream) {
  const int*   tok  = (const int*)d_in[0];
  const float* emb  = (const float*)d_in[1];
  const float* Wihf = (const float*)d_in[2];
  const float* Whhf = (const float*)d_in[3];
  const float* bihf = (const float*)d_in[4];
  const float* bhhf = (const float*)d_in[5];
  const float* Wihb = (const float*)d_in[6];
  const float* Whhb = (const float*)d_in[7];
  const float* bihb = (const float*)d_in[8];
  const float* bhhb = (const float*)d_in[9];
  const float* Wo   = (const float*)d_in[10];
  const float* bo   = (const float*)d_in[11];
  float* out = (float*)d_out;

  char* ws = (char*)d_ws;
  unsigned short* xqf = (unsigned short*)ws;                                  // 64 MiB
  unsigned short* xqb = (unsigned short*)(ws + (size_t)NROW * GDIM * 2);      // 64 MiB
  unsigned short* hq  = (unsigned short*)(ws + (size_t)NROW * GDIM * 4);      // 32 MiB
  // packed W parked in d_out (1 MiB of 8 MiB); k_out fully overwrites d_out later
  unsigned short* wpk = (unsigned short*)d_out;

  k_pack<<<256, 256, 0, stream>>>(Whhf, Whhb, wpk);
  k_proj<<<dim3(128, 2), 512, 0, stream>>>(tok, emb, Wihf, bihf, bhhf,
                                           Wihb, bihb, bhhb, xqf, xqb);
  k_lstm<<<8, 1024, 0, stream>>>(wpk, xqf, xqb, hq);
  k_out<<<512, 256, 0, stream>>>(hq, Wo, bo, out);
}